// Round 2
// baseline (1306.341 us; speedup 1.0000x reference)
//
#include <hip/hip_runtime.h>

// RIMCell forward, MI355X. Round 2: f32 inputs/outputs (per reference dtypes),
// bf16 internal intermediates. B=256, D=512, H=512, U=24, K=8, IK=64, IV=400,
// NIH=1, CK=CQ=32, NCH=4, CV=512.

typedef unsigned short u16;

__device__ __forceinline__ float u2f(u16 u) {
    union { unsigned int i; float f; } c; c.i = ((unsigned int)u) << 16; return c.f;
}
__device__ __forceinline__ u16 f2u(float f) {
    union { float f; unsigned int i; } c; c.f = f;
    unsigned int i = c.i;
    return (u16)((i + 0x7FFFu + ((i >> 16) & 1u)) >> 16);  // RNE
}

// ---------------- Stage 1: k0[b,64] = x[b]@key_w + key_b ; v0[b,400] = x[b]@value_w + value_b
__global__ __launch_bounds__(256) void kv_kernel(
    const float* __restrict__ x, const float* __restrict__ key_w, const float* __restrict__ key_b,
    const float* __restrict__ value_w, const float* __restrict__ value_b,
    float* __restrict__ k0, float* __restrict__ v0)
{
    __shared__ float xs[512];
    const int b = blockIdx.x, tid = threadIdx.x;
    for (int i = tid; i < 512; i += 256) xs[i] = x[b * 512 + i];
    __syncthreads();
    if (tid < 64) {
        float acc = 0.f;
        for (int d = 0; d < 512; ++d) acc += xs[d] * key_w[d * 64 + tid];
        k0[b * 64 + tid] = acc + key_b[tid];
    }
    for (int v = tid; v < 400; v += 256) {
        float acc = 0.f;
        for (int d = 0; d < 512; ++d) acc += xs[d] * value_w[d * 400 + v];
        v0[b * 400 + v] = acc + value_b[v];
    }
}

// ---------------- Stage 2: scores[b,u,0] = (hs[b,u]@query_w[u])·k0[b]/8 ; scores[b,u,1] = q·key_b/8
__global__ __launch_bounds__(64) void qscore_kernel(
    const float* __restrict__ hs, const float* __restrict__ query_w,
    const float* __restrict__ k0, const float* __restrict__ key_b,
    float* __restrict__ scores)
{
    __shared__ float hsu[512];
    const int u = blockIdx.x, b = blockIdx.y, lane = threadIdx.x;
    const float* h = hs + ((size_t)(b * 24 + u)) * 512;
    for (int i = lane; i < 512; i += 64) hsu[i] = h[i];
    __syncthreads();
    const float* qw = query_w + (size_t)u * 512 * 64 + lane;
    float q = 0.f;
    for (int d = 0; d < 512; ++d) q += hsu[d] * qw[(size_t)d * 64];
    float p0 = q * k0[b * 64 + lane];
    float p1 = q * key_b[lane];
    #pragma unroll
    for (int off = 32; off > 0; off >>= 1) {
        p0 += __shfl_down(p0, off);
        p1 += __shfl_down(p1, off);
    }
    if (lane == 0) {
        scores[(b * 24 + u) * 2 + 0] = p0 * 0.125f;
        scores[(b * 24 + u) * 2 + 1] = p1 * 0.125f;
    }
}

// ---------------- Stage 3: stable top-8 mask over scores[:,:,0]; probs = softmax over t(2)
__global__ __launch_bounds__(64) void topk_kernel(
    const float* __restrict__ scores, float* __restrict__ mask, float* __restrict__ probs)
{
    __shared__ float s0[24];
    const int b = blockIdx.x, tid = threadIdx.x;
    if (tid < 24) s0[tid] = scores[(b * 24 + tid) * 2];
    __syncthreads();
    if (tid < 24) {
        const float su = s0[tid];
        int rank = 0;
        for (int t = 0; t < 24; ++t) {
            float st = s0[t];
            rank += (st > su) || (st == su && t < tid);
        }
        mask[b * 24 + tid] = (rank < 8) ? 1.f : 0.f;
        const float a = su, c = scores[(b * 24 + tid) * 2 + 1];
        const float m = fmaxf(a, c);
        const float e0 = expf(a - m), e1 = expf(c - m);
        const float inv = 1.f / (e0 + e1);
        probs[(b * 24 + tid) * 2 + 0] = e0 * inv;
        probs[(b * 24 + tid) * 2 + 1] = e1 * inv;
    }
}

// ---------------- Stage 4: inp[b,u,v] = (p0*v0[b,v] + p1*value_b[v]) * mask[b,u]   (bf16 out)
__global__ __launch_bounds__(256) void inp_kernel(
    const float* __restrict__ probs, const float* __restrict__ v0,
    const float* __restrict__ value_b, const float* __restrict__ mask,
    u16* __restrict__ inp)
{
    const int idx = blockIdx.x * 256 + threadIdx.x;  // exactly B*U*400
    const int v = idx % 400, bu = idx / 400, b = bu / 24;
    const float val = (probs[bu * 2] * v0[b * 400 + v] + probs[bu * 2 + 1] * value_b[v]) * mask[bu];
    inp[idx] = f2u(val);
}

// ---------------- f32 -> bf16 convert (hs -> hsb)
__global__ __launch_bounds__(256) void tobf16_kernel(
    const float* __restrict__ src, u16* __restrict__ dst)
{
    const int idx = blockIdx.x * 256 + threadIdx.x;
    dst[idx] = f2u(src[idx]);
}

// ---------------- Generic per-u batched GEMM: C[u] = A1[u]@B1[u] (+ A2[u]@B2[u])
// A bf16, B f32 (weights). 64x64 tile, 256 threads, 4x4 microtile, BK=16.
// mode 0: f32 store. mode 1: bf16 store. mode 2: co epilogue f32 (mask ? acc+ht : hs).
__global__ __launch_bounds__(256) void gemm_kernel(
    const u16* __restrict__ A1, int lda1, int aus1,
    const float* __restrict__ B1, int ldb1, int bus1, int K1,
    const u16* __restrict__ A2, int lda2, int aus2,
    const float* __restrict__ B2, int ldb2, int bus2, int K2,
    void* __restrict__ Cv, int ldc, int cus, int mode,
    const float* __restrict__ mask, const u16* __restrict__ ht, const float* __restrict__ hs_in)
{
    __shared__ float As[64][16];
    __shared__ float Bs[16][64];
    const int u = blockIdx.z;
    const int n0 = blockIdx.x * 64, m0 = blockIdx.y * 64;
    const int tid = threadIdx.x;
    const int tx = tid & 15, ty = tid >> 4;
    const int ar = tid >> 2, aq = (tid & 3) * 4;        // A-tile: row ar, 4 cols at aq
    const int bkr = tid >> 4, bc = (tid & 15) * 4;      // B-tile: k-row bkr, 4 cols at bc
    float acc[4][4] = {};

    for (int seg = 0; seg < 2; ++seg) {
        const int K = seg ? K2 : K1;
        if (K == 0) continue;
        const u16*   A  = (seg ? A2 : A1) + (size_t)u * (seg ? aus2 : aus1);
        const float* Bw = (seg ? B2 : B1) + (size_t)u * (seg ? bus2 : bus1);
        const int lda = seg ? lda2 : lda1;
        const int ldb = seg ? ldb2 : ldb1;
        A  += (size_t)(m0 + ar) * lda + aq;
        Bw += (size_t)bkr * ldb + n0 + bc;
        for (int k0 = 0; k0 < K; k0 += 16) {
            ushort4 av = *reinterpret_cast<const ushort4*>(A + k0);
            float4  bf = *reinterpret_cast<const float4*>(Bw + (size_t)k0 * ldb);
            float4 af = make_float4(u2f(av.x), u2f(av.y), u2f(av.z), u2f(av.w));
            *reinterpret_cast<float4*>(&As[ar][aq]) = af;
            *reinterpret_cast<float4*>(&Bs[bkr][bc]) = bf;
            __syncthreads();
            #pragma unroll
            for (int kk = 0; kk < 16; ++kk) {
                const float4 b4 = *reinterpret_cast<const float4*>(&Bs[kk][tx * 4]);
                const float a0 = As[ty * 4 + 0][kk];
                const float a1 = As[ty * 4 + 1][kk];
                const float a2 = As[ty * 4 + 2][kk];
                const float a3 = As[ty * 4 + 3][kk];
                acc[0][0] += a0 * b4.x; acc[0][1] += a0 * b4.y; acc[0][2] += a0 * b4.z; acc[0][3] += a0 * b4.w;
                acc[1][0] += a1 * b4.x; acc[1][1] += a1 * b4.y; acc[1][2] += a1 * b4.z; acc[1][3] += a1 * b4.w;
                acc[2][0] += a2 * b4.x; acc[2][1] += a2 * b4.y; acc[2][2] += a2 * b4.z; acc[2][3] += a2 * b4.w;
                acc[3][0] += a3 * b4.x; acc[3][1] += a3 * b4.y; acc[3][2] += a3 * b4.z; acc[3][3] += a3 * b4.w;
            }
            __syncthreads();
        }
    }

    const int mrow = m0 + ty * 4;
    const int ncol = n0 + tx * 4;
    if (mode == 0) {
        float* C = (float*)Cv + (size_t)u * cus;
        #pragma unroll
        for (int i = 0; i < 4; ++i) {
            float4 v = make_float4(acc[i][0], acc[i][1], acc[i][2], acc[i][3]);
            *reinterpret_cast<float4*>(&C[(size_t)(mrow + i) * ldc + ncol]) = v;
        }
    } else if (mode == 1) {
        u16* C = (u16*)Cv + (size_t)u * cus;
        #pragma unroll
        for (int i = 0; i < 4; ++i) {
            ushort4 v;
            v.x = f2u(acc[i][0]); v.y = f2u(acc[i][1]); v.z = f2u(acc[i][2]); v.w = f2u(acc[i][3]);
            *reinterpret_cast<ushort4*>(&C[(size_t)(mrow + i) * ldc + ncol]) = v;
        }
    } else {
        float* C = (float*)Cv + (size_t)u * cus;
        const u16*   htu = ht + (size_t)u * cus;
        const float* hsu = hs_in + (size_t)u * cus;
        #pragma unroll
        for (int i = 0; i < 4; ++i) {
            const int m = mrow + i;                  // m == batch index b
            const float mk = mask[m * 24 + u];
            const size_t base = (size_t)m * ldc + ncol;
            float4 o;
            if (mk != 0.f) {
                ushort4 tv = *reinterpret_cast<const ushort4*>(&htu[base]);
                o.x = acc[i][0] + u2f(tv.x);
                o.y = acc[i][1] + u2f(tv.y);
                o.z = acc[i][2] + u2f(tv.z);
                o.w = acc[i][3] + u2f(tv.w);
            } else {
                o = *reinterpret_cast<const float4*>(&hsu[base]);  // bit-exact passthrough
            }
            *reinterpret_cast<float4*>(&C[base]) = o;
        }
    }
}

// ---------------- Stage 6: LSTM gates; writes h_t (ws, bf16) and cs_new (d_out, f32 select)
__global__ __launch_bounds__(256) void gates_kernel(
    const float* __restrict__ preact, const float* __restrict__ cs,
    const float* __restrict__ mask,
    u16* __restrict__ ht, float* __restrict__ out_cs)
{
    const int idx = blockIdx.x * 256 + threadIdx.x;  // exactly B*U*512
    const int h = idx & 511, bu = idx >> 9;
    const float* pre = preact + (size_t)bu * 2048;
    const float it = 1.f / (1.f + expf(-pre[h]));
    const float ft = 1.f / (1.f + expf(-pre[512 + h]));
    const float ot = 1.f / (1.f + expf(-pre[1024 + h]));
    const float gt = tanhf(pre[1536 + h]);
    const float c = cs[idx] * ft + it * gt;
    ht[idx] = f2u(ot * tanhf(c));
    out_cs[idx] = (mask[bu] != 0.f) ? c : cs[idx];  // passthrough bit-exact when unmasked
}

// ---------------- Stage 10: per (u, head, b) attention over t=24; skip unmasked u (ctx unused there)
__global__ __launch_bounds__(64) void attn_kernel(
    const u16* __restrict__ qc, const u16* __restrict__ kc, const u16* __restrict__ vc,
    const float* __restrict__ mask, u16* __restrict__ ctx)
{
    const int u = blockIdx.x, nc = blockIdx.y, b = blockIdx.z;
    if (mask[b * 24 + u] == 0.f) return;  // uniform per block; ctx rows discarded by co epilogue
    const int lane = threadIdx.x;
    __shared__ float kcs[24][32];
    __shared__ float qv[32];
    __shared__ float ss[24];
    __shared__ float ps[24];
    for (int i = lane; i < 24 * 32; i += 64) {
        const int t = i >> 5, k = i & 31;
        kcs[t][k] = u2f(kc[((size_t)(b * 24 + t)) * 128 + nc * 32 + k]);
    }
    if (lane < 32) qv[lane] = u2f(qc[((size_t)(b * 24 + u)) * 128 + nc * 32 + lane]);
    __syncthreads();
    if (lane < 24) {
        float s = 0.f;
        for (int k = 0; k < 32; ++k) s += qv[k] * kcs[lane][k];
        ss[lane] = s * 0.17677669529663687f;  // 1/sqrt(32)
    }
    __syncthreads();
    float m = -1e30f;
    for (int t = 0; t < 24; ++t) m = fmaxf(m, ss[t]);
    float sum = 0.f;
    for (int t = 0; t < 24; ++t) sum += expf(ss[t] - m);
    const float inv = 1.f / sum;
    if (lane < 24) ps[lane] = expf(ss[lane] - m) * inv;
    __syncthreads();
    float acc[8] = {};
    const u16* vcb = vc + (size_t)b * 24 * 2048 + nc * 512 + lane;
    for (int t = 0; t < 24; ++t) {
        const float pt = ps[t];
        const u16* vr = vcb + (size_t)t * 2048;
        #pragma unroll
        for (int j = 0; j < 8; ++j) acc[j] += pt * u2f(vr[j * 64]);
    }
    u16* cb = ctx + ((size_t)(b * 24 + u)) * 2048 + nc * 512 + lane;
    #pragma unroll
    for (int j = 0; j < 8; ++j) cb[j * 64] = f2u(acc[j]);
}

extern "C" void kernel_launch(void* const* d_in, const int* in_sizes, int n_in,
                              void* d_out, int out_size, void* d_ws, size_t ws_size,
                              hipStream_t stream)
{
    (void)in_sizes; (void)n_in; (void)out_size; (void)ws_size;
    const float* x       = (const float*)d_in[0];
    const float* hs      = (const float*)d_in[1];
    const float* cs      = (const float*)d_in[2];
    const float* key_w   = (const float*)d_in[3];
    const float* key_b   = (const float*)d_in[4];
    const float* value_w = (const float*)d_in[5];
    const float* value_b = (const float*)d_in[6];
    const float* query_w = (const float*)d_in[7];
    const float* i2h_w   = (const float*)d_in[8];
    const float* h2h_w   = (const float*)d_in[9];
    const float* qc_w    = (const float*)d_in[10];
    const float* kc_w    = (const float*)d_in[11];
    const float* vc_w    = (const float*)d_in[12];
    const float* co_w    = (const float*)d_in[13];

    // ws layout (bytes); vc/ctx alias the dead preact region (25MB+25MB == 50MB)
    char* ws = (char*)d_ws;
    float* k0     = (float*)(ws + 0);          // 256*64*4    = 65536
    float* v0     = (float*)(ws + 65536);      // 256*400*4   = 409600
    float* scores = (float*)(ws + 475136);     // 256*24*2*4  = 49152
    float* probs  = (float*)(ws + 524288);     // 49152
    float* mask   = (float*)(ws + 573440);     // 256*24*4    = 24576
    u16*   inp    = (u16*)  (ws + 598016);     // 256*24*400*2 = 4915200
    float* preact = (float*)(ws + 5513216);    // 256*24*2048*4 = 50331648
    u16*   vc     = (u16*)  (ws + 5513216);    // alias (preact dead after gates)
    u16*   ctx    = (u16*)  (ws + 30679040);   // alias, second half
    u16*   ht     = (u16*)  (ws + 55844864);   // 256*24*512*2 = 6291456
    u16*   kc     = (u16*)  (ws + 62136320);   // 256*24*128*2 = 1572864
    u16*   qcb    = (u16*)  (ws + 63709184);   // 1572864
    u16*   hsb    = (u16*)  (ws + 65282048);   // 256*24*512*2 = 6291456 (total ~71.6MB)

    float* out_hs = (float*)d_out;
    float* out_cs = out_hs + (size_t)256 * 24 * 512;

    kv_kernel<<<256, 256, 0, stream>>>(x, key_w, key_b, value_w, value_b, k0, v0);
    qscore_kernel<<<dim3(24, 256), 64, 0, stream>>>(hs, query_w, k0, key_b, scores);
    topk_kernel<<<256, 64, 0, stream>>>(scores, mask, probs);
    inp_kernel<<<(256 * 24 * 400) / 256, 256, 0, stream>>>(probs, v0, value_b, mask, inp);
    tobf16_kernel<<<(256 * 24 * 512) / 256, 256, 0, stream>>>(hs, hsb);

    // preact = inp@i2h_w[u] + hs@h2h_w[u]   (M=256, N=2048, K=400+512)
    gemm_kernel<<<dim3(32, 4, 24), 256, 0, stream>>>(
        inp, 9600, 400, i2h_w, 2048, 400 * 2048, 400,
        hsb, 12288, 512, h2h_w, 2048, 512 * 2048, 512,
        preact, 49152, 2048, 0, nullptr, nullptr, nullptr);

    gates_kernel<<<12288, 256, 0, stream>>>(preact, cs, mask, ht, out_cs);

    // kc/qc: M=256, N=128, K=512
    gemm_kernel<<<dim3(2, 4, 24), 256, 0, stream>>>(
        ht, 12288, 512, kc_w, 128, 512 * 128, 512,
        nullptr, 0, 0, nullptr, 0, 0, 0,
        kc, 3072, 128, 1, nullptr, nullptr, nullptr);
    gemm_kernel<<<dim3(2, 4, 24), 256, 0, stream>>>(
        ht, 12288, 512, qc_w, 128, 512 * 128, 512,
        nullptr, 0, 0, nullptr, 0, 0, 0,
        qcb, 3072, 128, 1, nullptr, nullptr, nullptr);
    // vc: M=256, N=2048, K=512
    gemm_kernel<<<dim3(32, 4, 24), 256, 0, stream>>>(
        ht, 12288, 512, vc_w, 2048, 512 * 2048, 512,
        nullptr, 0, 0, nullptr, 0, 0, 0,
        vc, 49152, 2048, 1, nullptr, nullptr, nullptr);

    attn_kernel<<<dim3(24, 4, 256), 64, 0, stream>>>(qcb, kc, vc, mask, ctx);

    // hs_new = mask ? ctx@co_w[u] + h_t : hs   (M=256, N=512, K=2048)
    gemm_kernel<<<dim3(8, 4, 24), 256, 0, stream>>>(
        ctx, 49152, 2048, co_w, 512, 2048 * 512, 2048,
        nullptr, 0, 0, nullptr, 0, 0, 0,
        out_hs, 12288, 512, 2, mask, ht, hs);
}

// Round 3
// 830.433 us; speedup vs baseline: 1.5731x; 1.5731x over previous
//
#include <hip/hip_runtime.h>

// RIMCell forward, MI355X. Round 3: MFMA bf16 GEMMs (32x32x16), 128x128 tiles.
// f32 inputs/outputs; bf16 internal intermediates; weights converted f32->bf16
// in the LDS staging path. B=256, D=512, H=512, U=24, K=8, IK=64, IV=400,
// NIH=1, CK=CQ=32, NCH=4, CV=512.

typedef unsigned short u16;
typedef __bf16 bf16_t;
typedef bf16_t bf16x8 __attribute__((ext_vector_type(8)));
typedef float f32x16 __attribute__((ext_vector_type(16)));

union V8 { uint4 u; bf16x8 v; u16 us[8]; };

__device__ __forceinline__ float u2f(u16 u) {
    union { unsigned int i; float f; } c; c.i = ((unsigned int)u) << 16; return c.f;
}
__device__ __forceinline__ u16 f2u(float f) {
    union { float f; unsigned int i; } c; c.f = f;
    unsigned int i = c.i;
    return (u16)((i + 0x7FFFu + ((i >> 16) & 1u)) >> 16);  // RNE
}

// ---------------- Stage 1: k0[b,64] = x[b]@key_w + key_b ; v0[b,400] = x[b]@value_w + value_b
__global__ __launch_bounds__(256) void kv_kernel(
    const float* __restrict__ x, const float* __restrict__ key_w, const float* __restrict__ key_b,
    const float* __restrict__ value_w, const float* __restrict__ value_b,
    float* __restrict__ k0, float* __restrict__ v0)
{
    __shared__ float xs[512];
    const int b = blockIdx.x, tid = threadIdx.x;
    for (int i = tid; i < 512; i += 256) xs[i] = x[b * 512 + i];
    __syncthreads();
    if (tid < 64) {
        float acc = 0.f;
        for (int d = 0; d < 512; ++d) acc += xs[d] * key_w[d * 64 + tid];
        k0[b * 64 + tid] = acc + key_b[tid];
    }
    for (int v = tid; v < 400; v += 256) {
        float acc = 0.f;
        for (int d = 0; d < 512; ++d) acc += xs[d] * value_w[d * 400 + v];
        v0[b * 400 + v] = acc + value_b[v];
    }
}

// ---------------- Stage 2: scores[b,u,0] = (hs[b,u]@query_w[u])·k0[b]/8 ; scores[b,u,1] = q·key_b/8
__global__ __launch_bounds__(64) void qscore_kernel(
    const float* __restrict__ hs, const float* __restrict__ query_w,
    const float* __restrict__ k0, const float* __restrict__ key_b,
    float* __restrict__ scores)
{
    __shared__ float hsu[512];
    const int u = blockIdx.x, b = blockIdx.y, lane = threadIdx.x;
    const float* h = hs + ((size_t)(b * 24 + u)) * 512;
    for (int i = lane; i < 512; i += 64) hsu[i] = h[i];
    __syncthreads();
    const float* qw = query_w + (size_t)u * 512 * 64 + lane;
    float q = 0.f;
    for (int d = 0; d < 512; ++d) q += hsu[d] * qw[(size_t)d * 64];
    float p0 = q * k0[b * 64 + lane];
    float p1 = q * key_b[lane];
    #pragma unroll
    for (int off = 32; off > 0; off >>= 1) {
        p0 += __shfl_down(p0, off);
        p1 += __shfl_down(p1, off);
    }
    if (lane == 0) {
        scores[(b * 24 + u) * 2 + 0] = p0 * 0.125f;
        scores[(b * 24 + u) * 2 + 1] = p1 * 0.125f;
    }
}

// ---------------- Stage 3: stable top-8 mask; probs = softmax over t(2)
__global__ __launch_bounds__(64) void topk_kernel(
    const float* __restrict__ scores, float* __restrict__ mask, float* __restrict__ probs)
{
    __shared__ float s0[24];
    const int b = blockIdx.x, tid = threadIdx.x;
    if (tid < 24) s0[tid] = scores[(b * 24 + tid) * 2];
    __syncthreads();
    if (tid < 24) {
        const float su = s0[tid];
        int rank = 0;
        for (int t = 0; t < 24; ++t) {
            float st = s0[t];
            rank += (st > su) || (st == su && t < tid);
        }
        mask[b * 24 + tid] = (rank < 8) ? 1.f : 0.f;
        const float a = su, c = scores[(b * 24 + tid) * 2 + 1];
        const float m = fmaxf(a, c);
        const float e0 = expf(a - m), e1 = expf(c - m);
        const float inv = 1.f / (e0 + e1);
        probs[(b * 24 + tid) * 2 + 0] = e0 * inv;
        probs[(b * 24 + tid) * 2 + 1] = e1 * inv;
    }
}

// ---------------- Stage 4: inp[b,u,v] (stride 416, zero-padded cols 400..415), bf16
__global__ __launch_bounds__(256) void inp_kernel(
    const float* __restrict__ probs, const float* __restrict__ v0,
    const float* __restrict__ value_b, const float* __restrict__ mask,
    u16* __restrict__ inp)
{
    const int idx = blockIdx.x * 256 + threadIdx.x;  // exactly B*U*416
    const int v = idx % 416, bu = idx / 416, b = bu / 24;
    float val = 0.f;
    if (v < 400)
        val = (probs[bu * 2] * v0[b * 400 + v] + probs[bu * 2 + 1] * value_b[v]) * mask[bu];
    inp[idx] = f2u(val);
}

// ---------------- f32 -> bf16 convert (hs -> hsb)
__global__ __launch_bounds__(256) void tobf16_kernel(
    const float* __restrict__ src, u16* __restrict__ dst)
{
    const int idx = blockIdx.x * 256 + threadIdx.x;
    dst[idx] = f2u(src[idx]);
}

// ---------------- MFMA batched-per-u GEMM: C[u] = A1[u]@B1[u] (+ A2[u]@B2[u])
// A bf16 (ws, row-major, K-stride padded to mult of 32), B f32 weights (k-major).
// Block tile 128(M)x128(N), BK=32, 4 waves each 64x64 via 2x2 mfma_32x32x16_bf16.
// mode 0: f32 store. mode 1: bf16 store. mode 2: co epilogue (mask ? acc+ht : hs).
__global__ __launch_bounds__(256, 2) void mfma_gemm(
    const u16* __restrict__ A1, int lda1, int aus1,
    const float* __restrict__ B1, int ldb1, int bus1, int K1,
    const u16* __restrict__ A2, int lda2, int aus2,
    const float* __restrict__ B2, int ldb2, int bus2, int K2,
    void* __restrict__ Cv, int ldc, int cus, int mode,
    const float* __restrict__ mask, const u16* __restrict__ ht, const float* __restrict__ hs_in)
{
    __shared__ u16 As[128 * 40];   // rows padded 32->40 (80B): 2-way-only bank aliasing
    __shared__ u16 Bs[128 * 40];   // stored n-major, k-contiguous (transposed at stage)
    const int u = blockIdx.z;
    const int n0 = blockIdx.x * 128, m0 = blockIdx.y * 128;
    const int tid = threadIdx.x;
    // staging ids
    const int ar = tid >> 2, ac = (tid & 3) * 8;   // A: 4 threads/row, 64 rows/pass, 2 passes
    const int bn = tid & 127, bkg = (tid >> 7) * 16; // B: one n per thread, 16 k's
    // frag ids
    const int w = tid >> 6, lane = tid & 63;
    const int wm = (w >> 1) * 64, wn = (w & 1) * 64;
    const int fr = lane & 31, kh = (lane >> 5) * 8;

    f32x16 acc[2][2];
    #pragma unroll
    for (int i = 0; i < 2; ++i)
        #pragma unroll
        for (int j = 0; j < 2; ++j)
            #pragma unroll
            for (int r = 0; r < 16; ++r) acc[i][j][r] = 0.f;

    for (int seg = 0; seg < 2; ++seg) {
        const int K = seg ? K2 : K1;
        if (K == 0) continue;
        const u16*   A  = (seg ? A2 : A1) + (size_t)u * (seg ? aus2 : aus1);
        const float* Bw = (seg ? B2 : B1) + (size_t)u * (seg ? bus2 : bus1);
        const int lda = seg ? lda2 : lda1;
        const int ldb = seg ? ldb2 : ldb1;
        const int nsteps = (K + 31) >> 5;
        for (int s = 0; s < nsteps; ++s) {
            const int k0 = s << 5;
            __syncthreads();
            // ---- stage A (bf16 already; A buffer K-stride is padded, no guard)
            {
                const u16* ap = A + (size_t)(m0 + ar) * lda + k0 + ac;
                *(uint4*)&As[ar * 40 + ac]        = *(const uint4*)ap;
                *(uint4*)&As[(ar + 64) * 40 + ac] = *(const uint4*)(ap + (size_t)64 * lda);
            }
            // ---- stage B with f32->bf16 convert + transpose (n-major, k-contiguous)
            {
                const float* bp = Bw + (size_t)(k0 + bkg) * ldb + n0 + bn;
                V8 lo, hi;
                if (k0 + 32 <= K) {
                    #pragma unroll
                    for (int j = 0; j < 8; ++j) lo.us[j] = f2u(bp[(size_t)j * ldb]);
                    #pragma unroll
                    for (int j = 0; j < 8; ++j) hi.us[j] = f2u(bp[(size_t)(j + 8) * ldb]);
                } else {
                    #pragma unroll
                    for (int j = 0; j < 8; ++j) {
                        const int kg = k0 + bkg + j;
                        lo.us[j] = (kg < K) ? f2u(bp[(size_t)j * ldb]) : (u16)0;
                    }
                    #pragma unroll
                    for (int j = 0; j < 8; ++j) {
                        const int kg = k0 + bkg + 8 + j;
                        hi.us[j] = (kg < K) ? f2u(bp[(size_t)(j + 8) * ldb]) : (u16)0;
                    }
                }
                *(uint4*)&Bs[bn * 40 + bkg]     = lo.u;
                *(uint4*)&Bs[bn * 40 + bkg + 8] = hi.u;
            }
            __syncthreads();
            // ---- MFMA: 2 k-halves x (2x2 tiles)
            #pragma unroll
            for (int kk = 0; kk < 32; kk += 16) {
                V8 a0, a1, b0, b1;
                a0.u = *(const uint4*)&As[(wm + fr) * 40 + kk + kh];
                a1.u = *(const uint4*)&As[(wm + 32 + fr) * 40 + kk + kh];
                b0.u = *(const uint4*)&Bs[(wn + fr) * 40 + kk + kh];
                b1.u = *(const uint4*)&Bs[(wn + 32 + fr) * 40 + kk + kh];
                acc[0][0] = __builtin_amdgcn_mfma_f32_32x32x16_bf16(a0.v, b0.v, acc[0][0], 0, 0, 0);
                acc[0][1] = __builtin_amdgcn_mfma_f32_32x32x16_bf16(a0.v, b1.v, acc[0][1], 0, 0, 0);
                acc[1][0] = __builtin_amdgcn_mfma_f32_32x32x16_bf16(a1.v, b0.v, acc[1][0], 0, 0, 0);
                acc[1][1] = __builtin_amdgcn_mfma_f32_32x32x16_bf16(a1.v, b1.v, acc[1][1], 0, 0, 0);
            }
        }
    }

    // ---- epilogue. C/D map (verified m74/m101): col=lane&31, row=(reg&3)+8*(reg>>2)+4*(lane>>5)
    const int rbase = (lane >> 5) * 4;
    #pragma unroll
    for (int i = 0; i < 2; ++i) {
        #pragma unroll
        for (int j = 0; j < 2; ++j) {
            const int gn = n0 + wn + j * 32 + fr;
            #pragma unroll
            for (int r = 0; r < 16; ++r) {
                const int row = (r & 3) + 8 * (r >> 2) + rbase;
                const int gm = m0 + wm + i * 32 + row;
                const size_t idx = (size_t)u * cus + (size_t)gm * ldc + gn;
                if (mode == 0) {
                    ((float*)Cv)[idx] = acc[i][j][r];
                } else if (mode == 1) {
                    ((u16*)Cv)[idx] = f2u(acc[i][j][r]);
                } else {
                    const float mk = mask[gm * 24 + u];
                    ((float*)Cv)[idx] = (mk != 0.f) ? (acc[i][j][r] + u2f(ht[idx])) : hs_in[idx];
                }
            }
        }
    }
}

// ---------------- Stage 6: LSTM gates; writes h_t (ws, bf16) and cs_new (d_out, f32 select)
__global__ __launch_bounds__(256) void gates_kernel(
    const float* __restrict__ preact, const float* __restrict__ cs,
    const float* __restrict__ mask,
    u16* __restrict__ ht, float* __restrict__ out_cs)
{
    const int idx = blockIdx.x * 256 + threadIdx.x;  // exactly B*U*512
    const int h = idx & 511, bu = idx >> 9;
    const float* pre = preact + (size_t)bu * 2048;
    const float it = 1.f / (1.f + expf(-pre[h]));
    const float ft = 1.f / (1.f + expf(-pre[512 + h]));
    const float ot = 1.f / (1.f + expf(-pre[1024 + h]));
    const float gt = tanhf(pre[1536 + h]);
    const float c = cs[idx] * ft + it * gt;
    ht[idx] = f2u(ot * tanhf(c));
    out_cs[idx] = (mask[bu] != 0.f) ? c : cs[idx];  // passthrough bit-exact when unmasked
}

// ---------------- Stage 10: per (u, head, b) attention over t=24; skip unmasked u
__global__ __launch_bounds__(64) void attn_kernel(
    const u16* __restrict__ qc, const u16* __restrict__ kc, const u16* __restrict__ vc,
    const float* __restrict__ mask, u16* __restrict__ ctx)
{
    const int u = blockIdx.x, nc = blockIdx.y, b = blockIdx.z;
    if (mask[b * 24 + u] == 0.f) return;  // ctx rows discarded by co epilogue
    const int lane = threadIdx.x;
    __shared__ float kcs[24][32];
    __shared__ float qv[32];
    __shared__ float ss[24];
    __shared__ float ps[24];
    for (int i = lane; i < 24 * 32; i += 64) {
        const int t = i >> 5, k = i & 31;
        kcs[t][k] = u2f(kc[((size_t)(b * 24 + t)) * 128 + nc * 32 + k]);
    }
    if (lane < 32) qv[lane] = u2f(qc[((size_t)(b * 24 + u)) * 128 + nc * 32 + lane]);
    __syncthreads();
    if (lane < 24) {
        float s = 0.f;
        for (int k = 0; k < 32; ++k) s += qv[k] * kcs[lane][k];
        ss[lane] = s * 0.17677669529663687f;  // 1/sqrt(32)
    }
    __syncthreads();
    float m = -1e30f;
    for (int t = 0; t < 24; ++t) m = fmaxf(m, ss[t]);
    float sum = 0.f;
    for (int t = 0; t < 24; ++t) sum += expf(ss[t] - m);
    const float inv = 1.f / sum;
    if (lane < 24) ps[lane] = expf(ss[lane] - m) * inv;
    __syncthreads();
    float acc[8] = {};
    const u16* vcb = vc + (size_t)b * 24 * 2048 + nc * 512 + lane;
    for (int t = 0; t < 24; ++t) {
        const float pt = ps[t];
        const u16* vr = vcb + (size_t)t * 2048;
        #pragma unroll
        for (int j = 0; j < 8; ++j) acc[j] += pt * u2f(vr[j * 64]);
    }
    u16* cb = ctx + ((size_t)(b * 24 + u)) * 2048 + nc * 512 + lane;
    #pragma unroll
    for (int j = 0; j < 8; ++j) cb[j * 64] = f2u(acc[j]);
}

extern "C" void kernel_launch(void* const* d_in, const int* in_sizes, int n_in,
                              void* d_out, int out_size, void* d_ws, size_t ws_size,
                              hipStream_t stream)
{
    (void)in_sizes; (void)n_in; (void)out_size; (void)ws_size;
    const float* x       = (const float*)d_in[0];
    const float* hs      = (const float*)d_in[1];
    const float* cs      = (const float*)d_in[2];
    const float* key_w   = (const float*)d_in[3];
    const float* key_b   = (const float*)d_in[4];
    const float* value_w = (const float*)d_in[5];
    const float* value_b = (const float*)d_in[6];
    const float* query_w = (const float*)d_in[7];
    const float* i2h_w   = (const float*)d_in[8];
    const float* h2h_w   = (const float*)d_in[9];
    const float* qc_w    = (const float*)d_in[10];
    const float* kc_w    = (const float*)d_in[11];
    const float* vc_w    = (const float*)d_in[12];
    const float* co_w    = (const float*)d_in[13];

    // ws layout (bytes); vc/ctx alias the dead preact region
    char* ws = (char*)d_ws;
    float* k0     = (float*)(ws + 0);          // 256*64*4    = 65536
    float* v0     = (float*)(ws + 65536);      // 256*400*4   = 409600
    float* scores = (float*)(ws + 475136);     // 256*24*2*4  = 49152
    float* probs  = (float*)(ws + 524288);     // 49152
    float* mask   = (float*)(ws + 573440);     // 256*24*4    = 24576
    u16*   inp    = (u16*)  (ws + 598016);     // 256*24*416*2 = 5111808 (K padded to 416)
    float* preact = (float*)(ws + 5709824);    // 256*24*2048*4 = 50331648
    u16*   vc     = (u16*)  (ws + 5709824);    // alias (preact dead after gates)
    u16*   ctx    = (u16*)  (ws + 30875648);   // alias, second half
    u16*   ht     = (u16*)  (ws + 56041472);   // 256*24*512*2 = 6291456
    u16*   kc     = (u16*)  (ws + 62332928);   // 256*24*128*2 = 1572864
    u16*   qcb    = (u16*)  (ws + 63905792);   // 1572864
    u16*   hsb    = (u16*)  (ws + 65478656);   // 6291456 (total ~71.8MB)

    float* out_hs = (float*)d_out;
    float* out_cs = out_hs + (size_t)256 * 24 * 512;

    kv_kernel<<<256, 256, 0, stream>>>(x, key_w, key_b, value_w, value_b, k0, v0);
    qscore_kernel<<<dim3(24, 256), 64, 0, stream>>>(hs, query_w, k0, key_b, scores);
    topk_kernel<<<256, 64, 0, stream>>>(scores, mask, probs);
    inp_kernel<<<(256 * 24 * 416) / 256, 256, 0, stream>>>(probs, v0, value_b, mask, inp);
    tobf16_kernel<<<(256 * 24 * 512) / 256, 256, 0, stream>>>(hs, hsb);

    // preact = inp@i2h_w[u] + hs@h2h_w[u]   (M=256, N=2048, K=400+512)
    mfma_gemm<<<dim3(16, 2, 24), 256, 0, stream>>>(
        inp, 9984, 416, i2h_w, 2048, 400 * 2048, 400,
        hsb, 12288, 512, h2h_w, 2048, 512 * 2048, 512,
        preact, 49152, 2048, 0, nullptr, nullptr, nullptr);

    gates_kernel<<<12288, 256, 0, stream>>>(preact, cs, mask, ht, out_cs);

    // kc/qc: M=256, N=128, K=512
    mfma_gemm<<<dim3(1, 2, 24), 256, 0, stream>>>(
        ht, 12288, 512, kc_w, 128, 512 * 128, 512,
        nullptr, 0, 0, nullptr, 0, 0, 0,
        kc, 3072, 128, 1, nullptr, nullptr, nullptr);
    mfma_gemm<<<dim3(1, 2, 24), 256, 0, stream>>>(
        ht, 12288, 512, qc_w, 128, 512 * 128, 512,
        nullptr, 0, 0, nullptr, 0, 0, 0,
        qcb, 3072, 128, 1, nullptr, nullptr, nullptr);
    // vc: M=256, N=2048, K=512
    mfma_gemm<<<dim3(16, 2, 24), 256, 0, stream>>>(
        ht, 12288, 512, vc_w, 2048, 512 * 2048, 512,
        nullptr, 0, 0, nullptr, 0, 0, 0,
        vc, 49152, 2048, 1, nullptr, nullptr, nullptr);

    attn_kernel<<<dim3(24, 4, 256), 64, 0, stream>>>(qcb, kc, vc, mask, ctx);

    // hs_new = mask ? ctx@co_w[u] + h_t : hs   (M=256, N=512, K=2048)
    mfma_gemm<<<dim3(4, 2, 24), 256, 0, stream>>>(
        ctx, 49152, 2048, co_w, 512, 2048 * 512, 2048,
        nullptr, 0, 0, nullptr, 0, 0, 0,
        out_hs, 12288, 512, 2, mask, ht, hs);
}